// Round 7
// baseline (221.055 us; speedup 1.0000x reference)
//
#include <hip/hip_runtime.h>
#include <math.h>

#ifndef M_PI
#define M_PI 3.14159265358979323846
#endif

// SPH solver step — pull formulation, zero global atomics, MLP-batched.
// Round-6 lesson: compute kernels were latency-bound (VALUBusy 15%) because
// each thread's loop iteration was a dependent chain with MLP=1. This round
// batches 8 edges/thread: 8 pair loads, then 8-16 independent 64B gathers in
// flight, then compute. Same for split/hist load->LDS-atomic chains (batch 4).
// Reference facts exploited:
//   * v_i - u_i == 0  -> transport stress term Ar == 0 exactly
//   * p_bg_i == 0     -> dvdt == 0 exactly (cols 5..7 written as zeros)
//   * eta_i == eta_j  -> eta_ij compile-time constant
//   * p = 100*(rho-1) -> j-side record {r,rho | v,p} is 32B, one 64B line
static constexpr float kSigma = (float)(3.0 / 359.0 / M_PI);  // H = 1
static constexpr float kPRef  = 100.0f;
static constexpr float kEps   = 1e-8f;
static constexpr float kEta   = (float)(2.0 * 0.01 * 0.01 / (0.01 + 0.01 + 1e-8));

#define CHUNKH 4096   // hist granularity (782 blocks)
#define CHUNKS 8192   // split granularity = 2 hist chunks (long write runs)
#define NSUB   4      // compute sub-blocks per coarse bin (~8 edges/thread)
#define BAT    8      // compute batch depth (MLP)

__device__ __forceinline__ float pow5f(float t) { float t2 = t * t; return t2 * t2 * t; }
__device__ __forceinline__ float pow4f(float t) { float t2 = t * t; return t2 * t2; }

// ---------------- pack positions into 16B records ----------------
__global__ void k_pack(const float* __restrict__ r, float4* __restrict__ pos4, int n) {
    int i = blockIdx.x * blockDim.x + threadIdx.x;
    if (i >= n) return;
    pos4[i] = make_float4(r[3 * i], r[3 * i + 1], r[3 * i + 2], 0.f);
}

// ---------------- coarse histogram: LDS atomics only, batch-4 --------------
__global__ void k_hist(const int* __restrict__ i_s, int* __restrict__ ghist,
                       int nbAh, int nbins, int E, int shift) {
    __shared__ int h[512];
    int t = threadIdx.x, blk = blockIdx.x;
    for (int b = t; b < nbins; b += 256) h[b] = 0;
    __syncthreads();
    int base = blk * CHUNKH;
    int end = min(base + CHUNKH, E);
    for (int kb = base; kb < end; kb += 256 * 4) {
        int iv[4];
#pragma unroll
        for (int b = 0; b < 4; b++) {
            int k = kb + b * 256 + t;
            iv[b] = (k < end) ? i_s[k] : -1;
        }
#pragma unroll
        for (int b = 0; b < 4; b++)
            if (iv[b] >= 0) atomicAdd(&h[iv[b] >> shift], 1);
    }
    __syncthreads();
    for (int b = t; b < nbins; b += 256)
        ghist[b * nbAh + blk] = h[b];   // bin-major for the scan
}

// ---------------- 2-kernel scan (final add folded into consumers) ----------
__global__ void k_scan_block(const int* __restrict__ in, int* __restrict__ out,
                             int* __restrict__ bsum, int m) {
    __shared__ int s[256];
    int t = threadIdx.x;
    int i = blockIdx.x * 256 + t;
    int x = (i < m) ? in[i] : 0;
    s[t] = x;
    __syncthreads();
    for (int d = 1; d < 256; d <<= 1) {
        int v = (t >= d) ? s[t - d] : 0;
        __syncthreads();
        s[t] += v;
        __syncthreads();
    }
    if (i < m) out[i] = s[t] - x;            // block-local exclusive
    if (t == 255) bsum[blockIdx.x] = s[255];
}

// single-block loop scan of block sums (handles any nb)
__global__ void k_scan_bsums(const int* __restrict__ bsum, int* __restrict__ bscan, int nb) {
    __shared__ int s[512];
    __shared__ int carry;
    int t = threadIdx.x;
    if (t == 0) carry = 0;
    __syncthreads();
    for (int base = 0; base < nb; base += 512) {
        int i = base + t;
        int x = (i < nb) ? bsum[i] : 0;
        s[t] = x;
        __syncthreads();
        for (int d = 1; d < 512; d <<= 1) {
            int v = (t >= d) ? s[t - d] : 0;
            __syncthreads();
            s[t] += v;
            __syncthreads();
        }
        if (i < nb) bscan[i] = s[t] - x + carry;
        __syncthreads();
        if (t == 511) carry += s[511];
        __syncthreads();
    }
}

__device__ __forceinline__ int scanned(const int* __restrict__ gscan,
                                       const int* __restrict__ bscan, int idx) {
    return gscan[idx] + bscan[idx >> 8];
}

// ---------------- coarse split: packed (slot,j) into coarse bins, batch-4 --
// Block b covers hist chunks 2b, 2b+1; cursors start at chunk 2b's offsets.
__global__ void k_split(const int* __restrict__ i_s, const int* __restrict__ j_s,
                        const int* __restrict__ gscan, const int* __restrict__ bscan,
                        int* __restrict__ pairs, int nbAh, int nbins, int E,
                        int shift, int jbits) {
    __shared__ int cur[512];
    int t = threadIdx.x, blk = blockIdx.x;
    for (int b = t; b < nbins; b += 512)
        cur[b] = scanned(gscan, bscan, b * nbAh + 2 * blk);
    __syncthreads();
    int fmask = (1 << shift) - 1;
    int base = blk * CHUNKS;
    int end = min(base + CHUNKS, E);
    for (int kb = base; kb < end; kb += 512 * 4) {
        int iv[4], jv[4];
#pragma unroll
        for (int b = 0; b < 4; b++) {
            int k = kb + b * 512 + t;
            iv[b] = (k < end) ? i_s[k] : -1;
            jv[b] = (k < end) ? j_s[k] : 0;
        }
#pragma unroll
        for (int b = 0; b < 4; b++) {
            if (iv[b] < 0) continue;
            int pos = atomicAdd(&cur[iv[b] >> shift], 1);      // LDS atomic
            pairs[pos] = ((iv[b] & fmask) << jbits) | jv[b];
        }
    }
}

// ---------------- pass 1: density — NSUB sub-blocks per bin, batch-8 -------
__global__ void k_rho_bin(const float4* __restrict__ pos4, const int* __restrict__ pairs,
                          const int* __restrict__ gscan, const int* __restrict__ bscan,
                          float* __restrict__ part_rho, int nbAh, int n, int E,
                          int shift, int jbits, int nbins) {
    __shared__ float srho[512];
    __shared__ float4 spos[512];
    __shared__ int sse[2];
    int bin = blockIdx.x >> 2, sub = blockIdx.x & (NSUB - 1);
    int t = threadIdx.x;
    int slots = 1 << shift;
    int lo = bin << shift;
    for (int s0 = t; s0 < slots; s0 += 256) {
        srho[s0] = 0.f;
        int ii = lo + s0;
        spos[s0] = (ii < n) ? pos4[ii] : make_float4(0.f, 0.f, 0.f, 0.f);
    }
    if (t == 0) {
        sse[0] = scanned(gscan, bscan, bin * nbAh);
        sse[1] = (bin + 1 < nbins) ? scanned(gscan, bscan, (bin + 1) * nbAh) : E;
    }
    __syncthreads();
    int s = sse[0], len = sse[1] - sse[0];
    int k0 = s + (int)((long)len * sub / NSUB);
    int k1 = s + (int)((long)len * (sub + 1) / NSUB);
    int jm = (1 << jbits) - 1;
    for (int kb = k0; kb < k1; kb += 256 * BAT) {
        int pr[BAT];
#pragma unroll
        for (int b = 0; b < BAT; b++) {
            int k = kb + b * 256 + t;
            pr[b] = (k < k1) ? pairs[k] : -1;          // coalesced
        }
        float4 rj[BAT];
#pragma unroll
        for (int b = 0; b < BAT; b++)
            if (pr[b] >= 0) rj[b] = pos4[pr[b] & jm];  // 8 gathers in flight
#pragma unroll
        for (int b = 0; b < BAT; b++) {
            if (pr[b] < 0) continue;
            int slot = pr[b] >> jbits;
            float4 ri = spos[slot];
            float dx = ri.x - rj[b].x, dy = ri.y - rj[b].y, dz = ri.z - rj[b].z;
            float d = sqrtf(dx * dx + dy * dy + dz * dz);
            float t1 = fmaxf(1.f - d, 0.f);
            float t2 = fmaxf(2.f - d, 0.f);
            float t3 = fmaxf(3.f - d, 0.f);
            float w = kSigma * (pow5f(t3) - 6.f * pow5f(t2) + 15.f * pow5f(t1));
            atomicAdd(&srho[slot], w);                 // LDS float atomic
        }
    }
    __syncthreads();
    for (int s0 = t; s0 < slots; s0 += 256) {
        int ii = lo + s0;
        if (ii < n) part_rho[(size_t)sub * n + ii] = srho[s0];   // coalesced
    }
}

// ---------------- reduce rho partials; fused per-particle state -------------
__global__ void k_reduce_rho(const float* __restrict__ part_rho,
                             const float4* __restrict__ pos4, const float* __restrict__ v,
                             float4* __restrict__ pv8, float* __restrict__ out, int n) {
    int i = blockIdx.x * blockDim.x + threadIdx.x;
    if (i >= n) return;
    float rh = 0.f;
    for (int s = 0; s < NSUB; s++) rh += part_rho[(size_t)s * n + i];
    float pp = kPRef * (rh - 1.0f);
    float4 sp = pos4[i];
    pv8[2 * i]     = make_float4(sp.x, sp.y, sp.z, rh);
    pv8[2 * i + 1] = make_float4(v[3 * i], v[3 * i + 1], v[3 * i + 2], pp);
    float* o = out + (size_t)i * 8;
    o[0] = rh;
    o[1] = pp;
    o[5] = 0.f; o[6] = 0.f; o[7] = 0.f;      // dvdt == 0 exactly
}

// ---------------- pass 2: acceleration — NSUB sub-blocks per bin, batch-8 --
__global__ void k_acc_bin(const float4* __restrict__ pv8, const int* __restrict__ pairs,
                          const int* __restrict__ gscan, const int* __restrict__ bscan,
                          float4* __restrict__ part_acc4, int nbAh, int n, int E,
                          int shift, int jbits, int nbins) {
    __shared__ float sax[512], say[512], saz[512];
    __shared__ float4 sab[1024];             // {r,rho | v,p} interleaved per slot
    __shared__ int sse[2];
    int bin = blockIdx.x >> 2, sub = blockIdx.x & (NSUB - 1);
    int t = threadIdx.x;
    int slots = 1 << shift;
    int lo = bin << shift;
    for (int s0 = t; s0 < slots; s0 += 256) { sax[s0] = 0.f; say[s0] = 0.f; saz[s0] = 0.f; }
    for (int q = t; q < 2 * slots; q += 256) {
        int gi = 2 * lo + q;
        sab[q] = (gi < 2 * n) ? pv8[gi] : make_float4(1.f, 1.f, 1.f, 1.f);
    }
    if (t == 0) {
        sse[0] = scanned(gscan, bscan, bin * nbAh);
        sse[1] = (bin + 1 < nbins) ? scanned(gscan, bscan, (bin + 1) * nbAh) : E;
    }
    __syncthreads();
    int s = sse[0], len = sse[1] - sse[0];
    int k0 = s + (int)((long)len * sub / NSUB);
    int k1 = s + (int)((long)len * (sub + 1) / NSUB);
    int jm = (1 << jbits) - 1;
    for (int kb = k0; kb < k1; kb += 256 * BAT) {
        int pr[BAT];
#pragma unroll
        for (int b = 0; b < BAT; b++) {
            int k = kb + b * 256 + t;
            pr[b] = (k < k1) ? pairs[k] : -1;          // coalesced
        }
        float4 aj[BAT], bj[BAT];
#pragma unroll
        for (int b = 0; b < BAT; b++) {
            if (pr[b] >= 0) {
                int j = pr[b] & jm;
                aj[b] = pv8[2 * j];                    // 16 gathers in flight,
                bj[b] = pv8[2 * j + 1];                // both halves of one line
            }
        }
#pragma unroll
        for (int b = 0; b < BAT; b++) {
            if (pr[b] < 0) continue;
            int slot = pr[b] >> jbits;
            float4 ai = sab[2 * slot];
            float4 bi = sab[2 * slot + 1];
            float rho_i = ai.w, p_i = bi.w;
            float rho_j = aj[b].w, p_j = bj[b].w;
            float dx = ai.x - aj[b].x, dy = ai.y - aj[b].y, dz = ai.z - aj[b].z;
            float d = sqrtf(dx * dx + dy * dy + dz * dz);
            float t1 = fmaxf(1.f - d, 0.f);
            float t2 = fmaxf(2.f - d, 0.f);
            float t3 = fmaxf(3.f - d, 0.f);
            float gw = kSigma * (-5.f * pow4f(t3) + 30.f * pow4f(t2) - 75.f * pow4f(t1));
            float inv_i = 1.0f / rho_i, inv_j = 1.0f / rho_j;
            float c = (inv_i * inv_i + inv_j * inv_j) * gw / (d + kEps);
            float p_ij = (rho_j * p_i + rho_i * p_j) / (rho_i + rho_j);
            atomicAdd(&sax[slot], c * (kEta * (bi.x - bj[b].x) - p_ij * dx));
            atomicAdd(&say[slot], c * (kEta * (bi.y - bj[b].y) - p_ij * dy));
            atomicAdd(&saz[slot], c * (kEta * (bi.z - bj[b].z) - p_ij * dz));
        }
    }
    __syncthreads();
    for (int s0 = t; s0 < slots; s0 += 256) {
        int ii = lo + s0;
        if (ii < n)
            part_acc4[(size_t)sub * n + ii] = make_float4(sax[s0], say[s0], saz[s0], 0.f);
    }
}

// ---------------- reduce acc partials ----------------
__global__ void k_reduce_acc(const float4* __restrict__ part_acc4,
                             float* __restrict__ out, int n) {
    int i = blockIdx.x * blockDim.x + threadIdx.x;
    if (i >= n) return;
    float ax = 0.f, ay = 0.f, az = 0.f;
    for (int s = 0; s < NSUB; s++) {
        float4 p = part_acc4[(size_t)s * n + i];
        ax += p.x; ay += p.y; az += p.z;
    }
    float* o = out + (size_t)i * 8 + 2;
    o[0] = ax; o[1] = ay; o[2] = az;
}

// ---------------- launch ----------------
static inline char* wcarve(char*& ws, size_t bytes) {
    char* p = ws;
    ws += (bytes + 255) & ~(size_t)255;
    return p;
}

extern "C" void kernel_launch(void* const* d_in, const int* in_sizes, int n_in,
                              void* d_out, int out_size, void* d_ws, size_t ws_size,
                              hipStream_t stream) {
    const float* r = (const float*)d_in[0];
    const float* v = (const float*)d_in[1];
    const int* i_s = (const int*)d_in[2];
    const int* j_s = (const int*)d_in[3];
    int n = in_sizes[0] / 3;
    int E = in_sizes[2];
    float* out = (float*)d_out;

    int shift = 8;                                 // 256 particles per coarse bin
    int nbins = ((n - 1) >> shift) + 1;
    while (nbins > 512) { shift++; nbins = ((n - 1) >> shift) + 1; }  // safety
    int jbits = 1;
    while ((1 << jbits) < n) jbits++;              // 17 for n = 100k

    int nbAh = (E + CHUNKH - 1) / CHUNKH;          // 782 hist blocks
    int nbAs = (E + CHUNKS - 1) / CHUNKS;          // 391 split blocks
    int m = nbins * nbAh;                          // scan length (~306k)
    int nb2 = (m + 255) / 256;

    char* ws = (char*)d_ws;
    float4* pos4     = (float4*)wcarve(ws, (size_t)n * 16);
    float4* pv8      = (float4*)wcarve(ws, (size_t)n * 32);
    int*    ghist    = (int*)wcarve(ws, (size_t)m * 4);
    int*    gscan    = (int*)wcarve(ws, (size_t)m * 4);
    int*    bsum     = (int*)wcarve(ws, (size_t)nb2 * 4);
    int*    bscan    = (int*)wcarve(ws, (size_t)nb2 * 4);
    int*    pairs    = (int*)wcarve(ws, (size_t)E * 4);
    float*  part_rho = (float*)wcarve(ws, (size_t)NSUB * n * 4);
    float4* part_acc4= (float4*)wcarve(ws, (size_t)NSUB * n * 16);

    const int bs = 256;
    int gn = (n + bs - 1) / bs;

    k_pack<<<gn, bs, 0, stream>>>(r, pos4, n);
    k_hist<<<nbAh, 256, 0, stream>>>(i_s, ghist, nbAh, nbins, E, shift);
    k_scan_block<<<nb2, 256, 0, stream>>>(ghist, gscan, bsum, m);
    k_scan_bsums<<<1, 512, 0, stream>>>(bsum, bscan, nb2);
    k_split<<<nbAs, 512, 0, stream>>>(i_s, j_s, gscan, bscan, pairs, nbAh, nbins, E, shift, jbits);
    k_rho_bin<<<nbins * NSUB, 256, 0, stream>>>(pos4, pairs, gscan, bscan, part_rho, nbAh, n, E, shift, jbits, nbins);
    k_reduce_rho<<<gn, bs, 0, stream>>>(part_rho, pos4, v, pv8, out, n);
    k_acc_bin<<<nbins * NSUB, 256, 0, stream>>>(pv8, pairs, gscan, bscan, part_acc4, nbAh, n, E, shift, jbits, nbins);
    k_reduce_acc<<<gn, bs, 0, stream>>>(part_acc4, out, n);
}

// Round 8
// 199.811 us; speedup vs baseline: 1.1063x; 1.1063x over previous
//
#include <hip/hip_runtime.h>
#include <math.h>

#ifndef M_PI
#define M_PI 3.14159265358979323846
#endif

// SPH solver step — pull formulation, zero global atomics.
// Round-7 lessons: (a) BAT=8 overflowed registers (VGPR 48 < 64 needed) and
// the compiler serialized the batch; (b) oversized static LDS halved
// occupancy. Round-8: BAT=4, exact-size LDS, main/tail loops without
// conditionals, fp16 per-edge {dr,d} sidecar so the acc pass needs ONE
// divergent 16B gather {v_j,p_j} per edge (rho_j = p_j/100+1 recovered).
// Split rewritten as block-level LDS counting sort + dense run flush.
// Reference facts exploited:
//   * v_i - u_i == 0  -> transport stress term Ar == 0 exactly
//   * p_bg_i == 0     -> dvdt == 0 exactly (cols 5..7 written as zeros)
//   * eta_i == eta_j  -> eta_ij compile-time constant
//   * p = 100*(rho-1) -> rho_j recoverable from p_j (one 16B j-record in acc)
static constexpr float kSigma = (float)(3.0 / 359.0 / M_PI);  // H = 1
static constexpr float kPRef  = 100.0f;
static constexpr float kEps   = 1e-8f;
static constexpr float kEta   = (float)(2.0 * 0.01 * 0.01 / (0.01 + 0.01 + 1e-8));

#define CHUNK 4096    // edges per hist/split block
#define NSUB  4       // compute sub-blocks per coarse bin (~8 edges/thread)
#define BAT   4       // compute batch depth (register-feasible MLP)

typedef _Float16 hf4 __attribute__((ext_vector_type(4)));   // 8B {dx,dy,dz,d}

__device__ __forceinline__ float pow5f(float t) { float t2 = t * t; return t2 * t2 * t; }
__device__ __forceinline__ float pow4f(float t) { float t2 = t * t; return t2 * t2; }

// ---------------- pack positions into 16B records ----------------
__global__ void k_pack(const float* __restrict__ r, float4* __restrict__ pos4, int n) {
    int i = blockIdx.x * blockDim.x + threadIdx.x;
    if (i >= n) return;
    pos4[i] = make_float4(r[3 * i], r[3 * i + 1], r[3 * i + 2], 0.f);
}

// ---------------- coarse histogram: LDS atomics only, batch-4 --------------
__global__ void k_hist(const int* __restrict__ i_s, int* __restrict__ ghist,
                       int nbA, int nbins, int E, int shift) {
    __shared__ int h[512];
    int t = threadIdx.x, blk = blockIdx.x;
    for (int b = t; b < nbins; b += 256) h[b] = 0;
    __syncthreads();
    int base = blk * CHUNK;
    int end = min(base + CHUNK, E);
    for (int kb = base; kb < end; kb += 256 * 4) {
        int iv[4];
#pragma unroll
        for (int b = 0; b < 4; b++) {
            int k = kb + b * 256 + t;
            iv[b] = (k < end) ? i_s[k] : -1;
        }
#pragma unroll
        for (int b = 0; b < 4; b++)
            if (iv[b] >= 0) atomicAdd(&h[iv[b] >> shift], 1);
    }
    __syncthreads();
    for (int b = t; b < nbins; b += 256)
        ghist[b * nbA + blk] = h[b];   // bin-major for the scan
}

// ---------------- 2-kernel scan (final add folded into consumers) ----------
__global__ void k_scan_block(const int* __restrict__ in, int* __restrict__ out,
                             int* __restrict__ bsum, int m) {
    __shared__ int s[256];
    int t = threadIdx.x;
    int i = blockIdx.x * 256 + t;
    int x = (i < m) ? in[i] : 0;
    s[t] = x;
    __syncthreads();
    for (int d = 1; d < 256; d <<= 1) {
        int v = (t >= d) ? s[t - d] : 0;
        __syncthreads();
        s[t] += v;
        __syncthreads();
    }
    if (i < m) out[i] = s[t] - x;            // block-local exclusive
    if (t == 255) bsum[blockIdx.x] = s[255];
}

// single-block loop scan of block sums (handles any nb)
__global__ void k_scan_bsums(const int* __restrict__ bsum, int* __restrict__ bscan, int nb) {
    __shared__ int s[512];
    __shared__ int carry;
    int t = threadIdx.x;
    if (t == 0) carry = 0;
    __syncthreads();
    for (int base = 0; base < nb; base += 512) {
        int i = base + t;
        int x = (i < nb) ? bsum[i] : 0;
        s[t] = x;
        __syncthreads();
        for (int d = 1; d < 512; d <<= 1) {
            int v = (t >= d) ? s[t - d] : 0;
            __syncthreads();
            s[t] += v;
            __syncthreads();
        }
        if (i < nb) bscan[i] = s[t] - x + carry;
        __syncthreads();
        if (t == 511) carry += s[511];
        __syncthreads();
    }
}

__device__ __forceinline__ int scanned(const int* __restrict__ gscan,
                                       const int* __restrict__ bscan, int idx) {
    return gscan[idx] + bscan[idx >> 8];
}

// ---------------- split: block-level LDS counting sort + dense flush -------
// Phase A: load this block's per-bin counts from ghist, 512-entry LDS scan.
// Phase B: scatter packed (slot,j) into LDS stage ordered by bin.
// Phase C: flush stage to global; consecutive lanes write consecutive
// addresses within each bin run (dense sectors — round-4 lesson).
__global__ void k_split(const int* __restrict__ i_s, const int* __restrict__ j_s,
                        const int* __restrict__ ghist, const int* __restrict__ gscan,
                        const int* __restrict__ bscan, int* __restrict__ pairs,
                        int nbA, int nbins, int E, int shift, int jbits) {
    __shared__ int lofs[512];                 // scan workspace -> cursors
    __shared__ int ldelta[512];               // global_base - local_base
    __shared__ int stage[CHUNK];
    __shared__ unsigned short binof[CHUNK];
    int t = threadIdx.x, blk = blockIdx.x;
    int base = blk * CHUNK;
    int end = min(base + CHUNK, E);
    int cnt = end - base;

    int h0 = (t < nbins) ? ghist[t * nbA + blk] : 0;
    int h1 = (t + 256 < nbins) ? ghist[(t + 256) * nbA + blk] : 0;
    lofs[t] = h0;
    lofs[t + 256] = h1;
    __syncthreads();
    for (int d = 1; d < 512; d <<= 1) {       // inclusive scan, 512 via 2/thread
        int v0 = (t >= d) ? lofs[t - d] : 0;
        int v1 = ((t + 256) >= d) ? lofs[t + 256 - d] : 0;
        __syncthreads();
        lofs[t] += v0;
        lofs[t + 256] += v1;
        __syncthreads();
    }
    int e0 = lofs[t] - h0;                    // exclusive
    int e1 = lofs[t + 256] - h1;
    __syncthreads();
    lofs[t] = e0;                             // local cursors
    lofs[t + 256] = e1;
    if (t < nbins) ldelta[t] = scanned(gscan, bscan, t * nbA + blk) - e0;
    if (t + 256 < nbins) ldelta[t + 256] = scanned(gscan, bscan, (t + 256) * nbA + blk) - e1;
    __syncthreads();

    int fmask = (1 << shift) - 1;
    for (int kb = base; kb < end; kb += 256 * 4) {     // phase B, batch-4
        int iv[4], jv[4];
#pragma unroll
        for (int b = 0; b < 4; b++) {
            int k = kb + b * 256 + t;
            iv[b] = (k < end) ? i_s[k] : -1;
            jv[b] = (k < end) ? j_s[k] : 0;
        }
#pragma unroll
        for (int b = 0; b < 4; b++) {
            if (iv[b] < 0) continue;
            int bin = iv[b] >> shift;
            int pos = atomicAdd(&lofs[bin], 1);        // LDS atomic
            stage[pos] = ((iv[b] & fmask) << jbits) | jv[b];
            binof[pos] = (unsigned short)bin;
        }
    }
    __syncthreads();
    for (int x = t; x < cnt; x += 256)                 // phase C: dense flush
        pairs[x + ldelta[binof[x]]] = stage[x];
}

// ---------------- pass 1: density — NSUB sub-blocks per bin, batch-4 -------
// Also writes per-edge fp16 sidecar {dx,dy,dz,d} (coalesced 8B) for acc.
__global__ void k_rho_bin(const float4* __restrict__ pos4, const int* __restrict__ pairs,
                          const int* __restrict__ gscan, const int* __restrict__ bscan,
                          float* __restrict__ part_rho, hf4* __restrict__ aux,
                          int nbA, int n, int E, int shift, int jbits, int nbins) {
    __shared__ float srho[256];
    __shared__ float4 spos[256];
    __shared__ int sse[2];
    int bin = blockIdx.x >> 2, sub = blockIdx.x & (NSUB - 1);
    int t = threadIdx.x;
    int lo = bin << shift;
    srho[t] = 0.f;
    int ii = lo + t;
    spos[t] = (ii < n) ? pos4[ii] : make_float4(0.f, 0.f, 0.f, 0.f);
    if (t == 0) {
        sse[0] = scanned(gscan, bscan, bin * nbA);
        sse[1] = (bin + 1 < nbins) ? scanned(gscan, bscan, (bin + 1) * nbA) : E;
    }
    __syncthreads();
    int s = sse[0], len = sse[1] - sse[0];
    int k0 = s + (int)((long)len * sub / NSUB);
    int k1 = s + (int)((long)len * (sub + 1) / NSUB);
    int jm = (1 << jbits) - 1;
    int kb = k0;
    for (; kb + 256 * BAT <= k1; kb += 256 * BAT) {    // main: no conditionals
        int pr[BAT];
#pragma unroll
        for (int b = 0; b < BAT; b++) pr[b] = pairs[kb + b * 256 + t];
        float4 rj[BAT];
#pragma unroll
        for (int b = 0; b < BAT; b++) rj[b] = pos4[pr[b] & jm];   // MLP=4
#pragma unroll
        for (int b = 0; b < BAT; b++) {
            int slot = pr[b] >> jbits;
            float4 ri = spos[slot];
            float dx = ri.x - rj[b].x, dy = ri.y - rj[b].y, dz = ri.z - rj[b].z;
            float d = sqrtf(dx * dx + dy * dy + dz * dz);
            float t1 = fmaxf(1.f - d, 0.f);
            float t2 = fmaxf(2.f - d, 0.f);
            float t3 = fmaxf(3.f - d, 0.f);
            float w = kSigma * (pow5f(t3) - 6.f * pow5f(t2) + 15.f * pow5f(t1));
            atomicAdd(&srho[slot], w);                 // LDS float atomic
            hf4 h;
            h.x = (_Float16)dx; h.y = (_Float16)dy;
            h.z = (_Float16)dz; h.w = (_Float16)d;
            aux[kb + b * 256 + t] = h;                 // coalesced 8B
        }
    }
    for (int k = kb + t; k < k1; k += 256) {           // tail
        int pr = pairs[k];
        int slot = pr >> jbits;
        float4 rj = pos4[pr & jm];
        float4 ri = spos[slot];
        float dx = ri.x - rj.x, dy = ri.y - rj.y, dz = ri.z - rj.z;
        float d = sqrtf(dx * dx + dy * dy + dz * dz);
        float t1 = fmaxf(1.f - d, 0.f);
        float t2 = fmaxf(2.f - d, 0.f);
        float t3 = fmaxf(3.f - d, 0.f);
        float w = kSigma * (pow5f(t3) - 6.f * pow5f(t2) + 15.f * pow5f(t1));
        atomicAdd(&srho[slot], w);
        hf4 h;
        h.x = (_Float16)dx; h.y = (_Float16)dy;
        h.z = (_Float16)dz; h.w = (_Float16)d;
        aux[k] = h;
    }
    __syncthreads();
    if (ii < n) part_rho[(size_t)sub * n + ii] = srho[t];   // coalesced
}

// ---------------- reduce rho partials; fused per-particle state -------------
__global__ void k_reduce_rho(const float* __restrict__ part_rho,
                             const float* __restrict__ v,
                             float4* __restrict__ vp4, float* __restrict__ out, int n) {
    int i = blockIdx.x * blockDim.x + threadIdx.x;
    if (i >= n) return;
    float rh = 0.f;
    for (int s = 0; s < NSUB; s++) rh += part_rho[(size_t)s * n + i];
    float pp = kPRef * (rh - 1.0f);
    vp4[i] = make_float4(v[3 * i], v[3 * i + 1], v[3 * i + 2], pp);
    float* o = out + (size_t)i * 8;
    o[0] = rh;
    o[1] = pp;
    o[5] = 0.f; o[6] = 0.f; o[7] = 0.f;      // dvdt == 0 exactly
}

// ---------------- pass 2: acceleration — ONE divergent gather per edge -----
__global__ void k_acc_bin(const float4* __restrict__ vp4, const int* __restrict__ pairs,
                          const hf4* __restrict__ aux,
                          const int* __restrict__ gscan, const int* __restrict__ bscan,
                          float4* __restrict__ part_acc4, int nbA, int n, int E,
                          int shift, int jbits, int nbins) {
    __shared__ float sax[256], say[256], saz[256];
    __shared__ float4 svp[256];              // {v_i, p_i} per slot
    __shared__ int sse[2];
    int bin = blockIdx.x >> 2, sub = blockIdx.x & (NSUB - 1);
    int t = threadIdx.x;
    int lo = bin << shift;
    sax[t] = 0.f; say[t] = 0.f; saz[t] = 0.f;
    int ii = lo + t;
    svp[t] = (ii < n) ? vp4[ii] : make_float4(0.f, 0.f, 0.f, 0.f);
    if (t == 0) {
        sse[0] = scanned(gscan, bscan, bin * nbA);
        sse[1] = (bin + 1 < nbins) ? scanned(gscan, bscan, (bin + 1) * nbA) : E;
    }
    __syncthreads();
    int s = sse[0], len = sse[1] - sse[0];
    int k0 = s + (int)((long)len * sub / NSUB);
    int k1 = s + (int)((long)len * (sub + 1) / NSUB);
    int jm = (1 << jbits) - 1;
    int kb = k0;
    for (; kb + 256 * BAT <= k1; kb += 256 * BAT) {    // main: no conditionals
        int pr[BAT];
        hf4 hx[BAT];
#pragma unroll
        for (int b = 0; b < BAT; b++) {
            int k = kb + b * 256 + t;
            pr[b] = pairs[k];                          // coalesced
            hx[b] = aux[k];                            // coalesced 8B
        }
        float4 vj[BAT];
#pragma unroll
        for (int b = 0; b < BAT; b++) vj[b] = vp4[pr[b] & jm];   // MLP=4, 16B
#pragma unroll
        for (int b = 0; b < BAT; b++) {
            int slot = pr[b] >> jbits;
            float4 bi = svp[slot];
            float p_i = bi.w, p_j = vj[b].w;
            float rho_i = p_i * 0.01f + 1.0f;          // exact inverse of EoS
            float rho_j = p_j * 0.01f + 1.0f;
            float dx = (float)hx[b].x, dy = (float)hx[b].y, dz = (float)hx[b].z;
            float d = (float)hx[b].w;
            float t1 = fmaxf(1.f - d, 0.f);
            float t2 = fmaxf(2.f - d, 0.f);
            float t3 = fmaxf(3.f - d, 0.f);
            float gw = kSigma * (-5.f * pow4f(t3) + 30.f * pow4f(t2) - 75.f * pow4f(t1));
            float inv_i = 1.0f / rho_i, inv_j = 1.0f / rho_j;
            float c = (inv_i * inv_i + inv_j * inv_j) * gw / (d + kEps);
            float p_ij = (rho_j * p_i + rho_i * p_j) / (rho_i + rho_j);
            atomicAdd(&sax[slot], c * (kEta * (bi.x - vj[b].x) - p_ij * dx));
            atomicAdd(&say[slot], c * (kEta * (bi.y - vj[b].y) - p_ij * dy));
            atomicAdd(&saz[slot], c * (kEta * (bi.z - vj[b].z) - p_ij * dz));
        }
    }
    for (int k = kb + t; k < k1; k += 256) {           // tail
        int pr = pairs[k];
        hf4 hx = aux[k];
        int slot = pr >> jbits;
        float4 vj = vp4[pr & jm];
        float4 bi = svp[slot];
        float p_i = bi.w, p_j = vj.w;
        float rho_i = p_i * 0.01f + 1.0f;
        float rho_j = p_j * 0.01f + 1.0f;
        float dx = (float)hx.x, dy = (float)hx.y, dz = (float)hx.z;
        float d = (float)hx.w;
        float t1 = fmaxf(1.f - d, 0.f);
        float t2 = fmaxf(2.f - d, 0.f);
        float t3 = fmaxf(3.f - d, 0.f);
        float gw = kSigma * (-5.f * pow4f(t3) + 30.f * pow4f(t2) - 75.f * pow4f(t1));
        float inv_i = 1.0f / rho_i, inv_j = 1.0f / rho_j;
        float c = (inv_i * inv_i + inv_j * inv_j) * gw / (d + kEps);
        float p_ij = (rho_j * p_i + rho_i * p_j) / (rho_i + rho_j);
        atomicAdd(&sax[slot], c * (kEta * (bi.x - vj.x) - p_ij * dx));
        atomicAdd(&say[slot], c * (kEta * (bi.y - vj.y) - p_ij * dy));
        atomicAdd(&saz[slot], c * (kEta * (bi.z - vj.z) - p_ij * dz));
    }
    __syncthreads();
    if (ii < n)
        part_acc4[(size_t)sub * n + ii] = make_float4(sax[t], say[t], saz[t], 0.f);
}

// ---------------- reduce acc partials ----------------
__global__ void k_reduce_acc(const float4* __restrict__ part_acc4,
                             float* __restrict__ out, int n) {
    int i = blockIdx.x * blockDim.x + threadIdx.x;
    if (i >= n) return;
    float ax = 0.f, ay = 0.f, az = 0.f;
    for (int s = 0; s < NSUB; s++) {
        float4 p = part_acc4[(size_t)s * n + i];
        ax += p.x; ay += p.y; az += p.z;
    }
    float* o = out + (size_t)i * 8 + 2;
    o[0] = ax; o[1] = ay; o[2] = az;
}

// ---------------- launch ----------------
static inline char* wcarve(char*& ws, size_t bytes) {
    char* p = ws;
    ws += (bytes + 255) & ~(size_t)255;
    return p;
}

extern "C" void kernel_launch(void* const* d_in, const int* in_sizes, int n_in,
                              void* d_out, int out_size, void* d_ws, size_t ws_size,
                              hipStream_t stream) {
    const float* r = (const float*)d_in[0];
    const float* v = (const float*)d_in[1];
    const int* i_s = (const int*)d_in[2];
    const int* j_s = (const int*)d_in[3];
    int n = in_sizes[0] / 3;
    int E = in_sizes[2];
    float* out = (float*)d_out;

    int shift = 8;                                 // 256 particles per coarse bin
    int nbins = ((n - 1) >> shift) + 1;
    while (nbins > 512) { shift++; nbins = ((n - 1) >> shift) + 1; }  // safety
    int jbits = 1;
    while ((1 << jbits) < n) jbits++;              // 17 for n = 100k

    int nbA = (E + CHUNK - 1) / CHUNK;             // 782 hist/split blocks
    int m = nbins * nbA;                           // scan length (~306k)
    int nb2 = (m + 255) / 256;

    char* ws = (char*)d_ws;
    float4* pos4     = (float4*)wcarve(ws, (size_t)n * 16);
    float4* vp4      = (float4*)wcarve(ws, (size_t)n * 16);
    int*    ghist    = (int*)wcarve(ws, (size_t)m * 4);
    int*    gscan    = (int*)wcarve(ws, (size_t)m * 4);
    int*    bsum     = (int*)wcarve(ws, (size_t)nb2 * 4);
    int*    bscan    = (int*)wcarve(ws, (size_t)nb2 * 4);
    int*    pairs    = (int*)wcarve(ws, (size_t)E * 4);
    hf4*    aux      = (hf4*)wcarve(ws, (size_t)E * 8);
    float*  part_rho = (float*)wcarve(ws, (size_t)NSUB * n * 4);
    float4* part_acc4= (float4*)wcarve(ws, (size_t)NSUB * n * 16);

    const int bs = 256;
    int gn = (n + bs - 1) / bs;

    k_pack<<<gn, bs, 0, stream>>>(r, pos4, n);
    k_hist<<<nbA, 256, 0, stream>>>(i_s, ghist, nbA, nbins, E, shift);
    k_scan_block<<<nb2, 256, 0, stream>>>(ghist, gscan, bsum, m);
    k_scan_bsums<<<1, 512, 0, stream>>>(bsum, bscan, nb2);
    k_split<<<nbA, 256, 0, stream>>>(i_s, j_s, ghist, gscan, bscan, pairs, nbA, nbins, E, shift, jbits);
    k_rho_bin<<<nbins * NSUB, 256, 0, stream>>>(pos4, pairs, gscan, bscan, part_rho, aux, nbA, n, E, shift, jbits, nbins);
    k_reduce_rho<<<gn, bs, 0, stream>>>(part_rho, v, vp4, out, n);
    k_acc_bin<<<nbins * NSUB, 256, 0, stream>>>(vp4, pairs, aux, gscan, bscan, part_acc4, nbA, n, E, shift, jbits, nbins);
    k_reduce_acc<<<gn, bs, 0, stream>>>(part_acc4, out, n);
}

// Round 9
// 193.097 us; speedup vs baseline: 1.1448x; 1.0348x over previous
//
#include <hip/hip_runtime.h>
#include <math.h>

#ifndef M_PI
#define M_PI 3.14159265358979323846
#endif

// SPH solver step — pull formulation, zero global atomics.
// Round-8 model (verified): divergent-gather passes run at
// throughput = outstanding_lines / latency; 13 waves x MLP4 = 52/CU -> 12
// cyc/edge. Round-9: NSUB=8 (3128 blocks, balance/occupancy) and BAT=6 with
// __launch_bounds__(256,6) (VGPR<=84, no spill) -> ~144 outstanding/CU.
// Reference facts exploited:
//   * v_i - u_i == 0  -> transport stress term Ar == 0 exactly
//   * p_bg_i == 0     -> dvdt == 0 exactly (cols 5..7 written as zeros)
//   * eta_i == eta_j  -> eta_ij compile-time constant
//   * p = 100*(rho-1) -> rho_j recoverable from p_j (one 16B j-record in acc)
static constexpr float kSigma = (float)(3.0 / 359.0 / M_PI);  // H = 1
static constexpr float kPRef  = 100.0f;
static constexpr float kEps   = 1e-8f;
static constexpr float kEta   = (float)(2.0 * 0.01 * 0.01 / (0.01 + 0.01 + 1e-8));

#define CHUNK 4096    // edges per hist/split block
#define NSUB  8       // compute sub-blocks per coarse bin (~4 edges/thread)
#define BAT   6       // compute batch depth (MLP; ~7 VGPR/edge in acc)

typedef _Float16 hf4 __attribute__((ext_vector_type(4)));   // 8B {dx,dy,dz,d}

__device__ __forceinline__ float pow5f(float t) { float t2 = t * t; return t2 * t2 * t; }
__device__ __forceinline__ float pow4f(float t) { float t2 = t * t; return t2 * t2; }

// ---------------- pack positions into 16B records ----------------
__global__ void k_pack(const float* __restrict__ r, float4* __restrict__ pos4, int n) {
    int i = blockIdx.x * blockDim.x + threadIdx.x;
    if (i >= n) return;
    pos4[i] = make_float4(r[3 * i], r[3 * i + 1], r[3 * i + 2], 0.f);
}

// ---------------- coarse histogram: LDS atomics only, batch-4 --------------
__global__ void k_hist(const int* __restrict__ i_s, int* __restrict__ ghist,
                       int nbA, int nbins, int E, int shift) {
    __shared__ int h[512];
    int t = threadIdx.x, blk = blockIdx.x;
    for (int b = t; b < nbins; b += 256) h[b] = 0;
    __syncthreads();
    int base = blk * CHUNK;
    int end = min(base + CHUNK, E);
    for (int kb = base; kb < end; kb += 256 * 4) {
        int iv[4];
#pragma unroll
        for (int b = 0; b < 4; b++) {
            int k = kb + b * 256 + t;
            iv[b] = (k < end) ? i_s[k] : -1;
        }
#pragma unroll
        for (int b = 0; b < 4; b++)
            if (iv[b] >= 0) atomicAdd(&h[iv[b] >> shift], 1);
    }
    __syncthreads();
    for (int b = t; b < nbins; b += 256)
        ghist[b * nbA + blk] = h[b];   // bin-major for the scan
}

// ---------------- 2-kernel scan (final add folded into consumers) ----------
__global__ void k_scan_block(const int* __restrict__ in, int* __restrict__ out,
                             int* __restrict__ bsum, int m) {
    __shared__ int s[256];
    int t = threadIdx.x;
    int i = blockIdx.x * 256 + t;
    int x = (i < m) ? in[i] : 0;
    s[t] = x;
    __syncthreads();
    for (int d = 1; d < 256; d <<= 1) {
        int v = (t >= d) ? s[t - d] : 0;
        __syncthreads();
        s[t] += v;
        __syncthreads();
    }
    if (i < m) out[i] = s[t] - x;            // block-local exclusive
    if (t == 255) bsum[blockIdx.x] = s[255];
}

// single-block loop scan of block sums (handles any nb)
__global__ void k_scan_bsums(const int* __restrict__ bsum, int* __restrict__ bscan, int nb) {
    __shared__ int s[512];
    __shared__ int carry;
    int t = threadIdx.x;
    if (t == 0) carry = 0;
    __syncthreads();
    for (int base = 0; base < nb; base += 512) {
        int i = base + t;
        int x = (i < nb) ? bsum[i] : 0;
        s[t] = x;
        __syncthreads();
        for (int d = 1; d < 512; d <<= 1) {
            int v = (t >= d) ? s[t - d] : 0;
            __syncthreads();
            s[t] += v;
            __syncthreads();
        }
        if (i < nb) bscan[i] = s[t] - x + carry;
        __syncthreads();
        if (t == 511) carry += s[511];
        __syncthreads();
    }
}

__device__ __forceinline__ int scanned(const int* __restrict__ gscan,
                                       const int* __restrict__ bscan, int idx) {
    return gscan[idx] + bscan[idx >> 8];
}

// ---------------- split: block-level LDS counting sort + dense flush -------
__global__ void k_split(const int* __restrict__ i_s, const int* __restrict__ j_s,
                        const int* __restrict__ ghist, const int* __restrict__ gscan,
                        const int* __restrict__ bscan, int* __restrict__ pairs,
                        int nbA, int nbins, int E, int shift, int jbits) {
    __shared__ int lofs[512];                 // scan workspace -> cursors
    __shared__ int ldelta[512];               // global_base - local_base
    __shared__ int stage[CHUNK];
    __shared__ unsigned short binof[CHUNK];
    int t = threadIdx.x, blk = blockIdx.x;
    int base = blk * CHUNK;
    int end = min(base + CHUNK, E);
    int cnt = end - base;

    int h0 = (t < nbins) ? ghist[t * nbA + blk] : 0;
    int h1 = (t + 256 < nbins) ? ghist[(t + 256) * nbA + blk] : 0;
    lofs[t] = h0;
    lofs[t + 256] = h1;
    __syncthreads();
    for (int d = 1; d < 512; d <<= 1) {       // inclusive scan, 512 via 2/thread
        int v0 = (t >= d) ? lofs[t - d] : 0;
        int v1 = ((t + 256) >= d) ? lofs[t + 256 - d] : 0;
        __syncthreads();
        lofs[t] += v0;
        lofs[t + 256] += v1;
        __syncthreads();
    }
    int e0 = lofs[t] - h0;                    // exclusive
    int e1 = lofs[t + 256] - h1;
    __syncthreads();
    lofs[t] = e0;                             // local cursors
    lofs[t + 256] = e1;
    if (t < nbins) ldelta[t] = scanned(gscan, bscan, t * nbA + blk) - e0;
    if (t + 256 < nbins) ldelta[t + 256] = scanned(gscan, bscan, (t + 256) * nbA + blk) - e1;
    __syncthreads();

    int fmask = (1 << shift) - 1;
    for (int kb = base; kb < end; kb += 256 * 4) {     // batch-4
        int iv[4], jv[4];
#pragma unroll
        for (int b = 0; b < 4; b++) {
            int k = kb + b * 256 + t;
            iv[b] = (k < end) ? i_s[k] : -1;
            jv[b] = (k < end) ? j_s[k] : 0;
        }
#pragma unroll
        for (int b = 0; b < 4; b++) {
            if (iv[b] < 0) continue;
            int bin = iv[b] >> shift;
            int pos = atomicAdd(&lofs[bin], 1);        // LDS atomic
            stage[pos] = ((iv[b] & fmask) << jbits) | jv[b];
            binof[pos] = (unsigned short)bin;
        }
    }
    __syncthreads();
    for (int x = t; x < cnt; x += 256)                 // dense flush
        pairs[x + ldelta[binof[x]]] = stage[x];
}

// ---------------- pass 1: density — NSUB sub-blocks per bin, batch-6 -------
__global__ void __launch_bounds__(256, 6)
k_rho_bin(const float4* __restrict__ pos4, const int* __restrict__ pairs,
          const int* __restrict__ gscan, const int* __restrict__ bscan,
          float* __restrict__ part_rho, hf4* __restrict__ aux,
          int nbA, int n, int E, int shift, int jbits, int nbins) {
    __shared__ float srho[256];
    __shared__ float4 spos[256];
    __shared__ int sse[2];
    int bin = blockIdx.x >> 3, sub = blockIdx.x & (NSUB - 1);
    int t = threadIdx.x;
    int lo = bin << shift;
    srho[t] = 0.f;
    int ii = lo + t;
    spos[t] = (ii < n) ? pos4[ii] : make_float4(0.f, 0.f, 0.f, 0.f);
    if (t == 0) {
        sse[0] = scanned(gscan, bscan, bin * nbA);
        sse[1] = (bin + 1 < nbins) ? scanned(gscan, bscan, (bin + 1) * nbA) : E;
    }
    __syncthreads();
    int s = sse[0], len = sse[1] - sse[0];
    int k0 = s + (int)((long)len * sub / NSUB);
    int k1 = s + (int)((long)len * (sub + 1) / NSUB);
    int jm = (1 << jbits) - 1;
    int kb = k0;
    for (; kb + 256 * BAT <= k1; kb += 256 * BAT) {    // main: no conditionals
        int pr[BAT];
#pragma unroll
        for (int b = 0; b < BAT; b++) pr[b] = pairs[kb + b * 256 + t];
        float4 rj[BAT];
#pragma unroll
        for (int b = 0; b < BAT; b++) rj[b] = pos4[pr[b] & jm];   // MLP=BAT
#pragma unroll
        for (int b = 0; b < BAT; b++) {
            int slot = pr[b] >> jbits;
            float4 ri = spos[slot];
            float dx = ri.x - rj[b].x, dy = ri.y - rj[b].y, dz = ri.z - rj[b].z;
            float d = sqrtf(dx * dx + dy * dy + dz * dz);
            float t1 = fmaxf(1.f - d, 0.f);
            float t2 = fmaxf(2.f - d, 0.f);
            float t3 = fmaxf(3.f - d, 0.f);
            float w = kSigma * (pow5f(t3) - 6.f * pow5f(t2) + 15.f * pow5f(t1));
            atomicAdd(&srho[slot], w);                 // LDS float atomic
            hf4 h;
            h.x = (_Float16)dx; h.y = (_Float16)dy;
            h.z = (_Float16)dz; h.w = (_Float16)d;
            aux[kb + b * 256 + t] = h;                 // coalesced 8B
        }
    }
    for (int k = kb + t; k < k1; k += 256) {           // tail
        int pr = pairs[k];
        int slot = pr >> jbits;
        float4 rj = pos4[pr & jm];
        float4 ri = spos[slot];
        float dx = ri.x - rj.x, dy = ri.y - rj.y, dz = ri.z - rj.z;
        float d = sqrtf(dx * dx + dy * dy + dz * dz);
        float t1 = fmaxf(1.f - d, 0.f);
        float t2 = fmaxf(2.f - d, 0.f);
        float t3 = fmaxf(3.f - d, 0.f);
        float w = kSigma * (pow5f(t3) - 6.f * pow5f(t2) + 15.f * pow5f(t1));
        atomicAdd(&srho[slot], w);
        hf4 h;
        h.x = (_Float16)dx; h.y = (_Float16)dy;
        h.z = (_Float16)dz; h.w = (_Float16)d;
        aux[k] = h;
    }
    __syncthreads();
    if (ii < n) part_rho[(size_t)sub * n + ii] = srho[t];   // coalesced
}

// ---------------- reduce rho partials; fused per-particle state -------------
__global__ void k_reduce_rho(const float* __restrict__ part_rho,
                             const float* __restrict__ v,
                             float4* __restrict__ vp4, float* __restrict__ out, int n) {
    int i = blockIdx.x * blockDim.x + threadIdx.x;
    if (i >= n) return;
    float rh = 0.f;
    for (int s = 0; s < NSUB; s++) rh += part_rho[(size_t)s * n + i];
    float pp = kPRef * (rh - 1.0f);
    vp4[i] = make_float4(v[3 * i], v[3 * i + 1], v[3 * i + 2], pp);
    float* o = out + (size_t)i * 8;
    o[0] = rh;
    o[1] = pp;
    o[5] = 0.f; o[6] = 0.f; o[7] = 0.f;      // dvdt == 0 exactly
}

// ---------------- pass 2: acceleration — ONE divergent gather per edge -----
__global__ void __launch_bounds__(256, 6)
k_acc_bin(const float4* __restrict__ vp4, const int* __restrict__ pairs,
          const hf4* __restrict__ aux,
          const int* __restrict__ gscan, const int* __restrict__ bscan,
          float4* __restrict__ part_acc4, int nbA, int n, int E,
          int shift, int jbits, int nbins) {
    __shared__ float sax[256], say[256], saz[256];
    __shared__ float4 svp[256];              // {v_i, p_i} per slot
    __shared__ int sse[2];
    int bin = blockIdx.x >> 3, sub = blockIdx.x & (NSUB - 1);
    int t = threadIdx.x;
    int lo = bin << shift;
    sax[t] = 0.f; say[t] = 0.f; saz[t] = 0.f;
    int ii = lo + t;
    svp[t] = (ii < n) ? vp4[ii] : make_float4(0.f, 0.f, 0.f, 0.f);
    if (t == 0) {
        sse[0] = scanned(gscan, bscan, bin * nbA);
        sse[1] = (bin + 1 < nbins) ? scanned(gscan, bscan, (bin + 1) * nbA) : E;
    }
    __syncthreads();
    int s = sse[0], len = sse[1] - sse[0];
    int k0 = s + (int)((long)len * sub / NSUB);
    int k1 = s + (int)((long)len * (sub + 1) / NSUB);
    int jm = (1 << jbits) - 1;
    int kb = k0;
    for (; kb + 256 * BAT <= k1; kb += 256 * BAT) {    // main: no conditionals
        int pr[BAT];
        hf4 hx[BAT];
#pragma unroll
        for (int b = 0; b < BAT; b++) {
            int k = kb + b * 256 + t;
            pr[b] = pairs[k];                          // coalesced
            hx[b] = aux[k];                            // coalesced 8B
        }
        float4 vj[BAT];
#pragma unroll
        for (int b = 0; b < BAT; b++) vj[b] = vp4[pr[b] & jm];   // MLP=BAT, 16B
#pragma unroll
        for (int b = 0; b < BAT; b++) {
            int slot = pr[b] >> jbits;
            float4 bi = svp[slot];
            float p_i = bi.w, p_j = vj[b].w;
            float rho_i = p_i * 0.01f + 1.0f;          // exact inverse of EoS
            float rho_j = p_j * 0.01f + 1.0f;
            float dx = (float)hx[b].x, dy = (float)hx[b].y, dz = (float)hx[b].z;
            float d = (float)hx[b].w;
            float t1 = fmaxf(1.f - d, 0.f);
            float t2 = fmaxf(2.f - d, 0.f);
            float t3 = fmaxf(3.f - d, 0.f);
            float gw = kSigma * (-5.f * pow4f(t3) + 30.f * pow4f(t2) - 75.f * pow4f(t1));
            float inv_i = 1.0f / rho_i, inv_j = 1.0f / rho_j;
            float c = (inv_i * inv_i + inv_j * inv_j) * gw / (d + kEps);
            float p_ij = (rho_j * p_i + rho_i * p_j) / (rho_i + rho_j);
            atomicAdd(&sax[slot], c * (kEta * (bi.x - vj[b].x) - p_ij * dx));
            atomicAdd(&say[slot], c * (kEta * (bi.y - vj[b].y) - p_ij * dy));
            atomicAdd(&saz[slot], c * (kEta * (bi.z - vj[b].z) - p_ij * dz));
        }
    }
    for (int k = kb + t; k < k1; k += 256) {           // tail
        int pr = pairs[k];
        hf4 hx = aux[k];
        int slot = pr >> jbits;
        float4 vj = vp4[pr & jm];
        float4 bi = svp[slot];
        float p_i = bi.w, p_j = vj.w;
        float rho_i = p_i * 0.01f + 1.0f;
        float rho_j = p_j * 0.01f + 1.0f;
        float dx = (float)hx.x, dy = (float)hx.y, dz = (float)hx.z;
        float d = (float)hx.w;
        float t1 = fmaxf(1.f - d, 0.f);
        float t2 = fmaxf(2.f - d, 0.f);
        float t3 = fmaxf(3.f - d, 0.f);
        float gw = kSigma * (-5.f * pow4f(t3) + 30.f * pow4f(t2) - 75.f * pow4f(t1));
        float inv_i = 1.0f / rho_i, inv_j = 1.0f / rho_j;
        float c = (inv_i * inv_i + inv_j * inv_j) * gw / (d + kEps);
        float p_ij = (rho_j * p_i + rho_i * p_j) / (rho_i + rho_j);
        atomicAdd(&sax[slot], c * (kEta * (bi.x - vj.x) - p_ij * dx));
        atomicAdd(&say[slot], c * (kEta * (bi.y - vj.y) - p_ij * dy));
        atomicAdd(&saz[slot], c * (kEta * (bi.z - vj.z) - p_ij * dz));
    }
    __syncthreads();
    if (ii < n)
        part_acc4[(size_t)sub * n + ii] = make_float4(sax[t], say[t], saz[t], 0.f);
}

// ---------------- reduce acc partials ----------------
__global__ void k_reduce_acc(const float4* __restrict__ part_acc4,
                             float* __restrict__ out, int n) {
    int i = blockIdx.x * blockDim.x + threadIdx.x;
    if (i >= n) return;
    float ax = 0.f, ay = 0.f, az = 0.f;
    for (int s = 0; s < NSUB; s++) {
        float4 p = part_acc4[(size_t)s * n + i];
        ax += p.x; ay += p.y; az += p.z;
    }
    float* o = out + (size_t)i * 8 + 2;
    o[0] = ax; o[1] = ay; o[2] = az;
}

// ---------------- launch ----------------
static inline char* wcarve(char*& ws, size_t bytes) {
    char* p = ws;
    ws += (bytes + 255) & ~(size_t)255;
    return p;
}

extern "C" void kernel_launch(void* const* d_in, const int* in_sizes, int n_in,
                              void* d_out, int out_size, void* d_ws, size_t ws_size,
                              hipStream_t stream) {
    const float* r = (const float*)d_in[0];
    const float* v = (const float*)d_in[1];
    const int* i_s = (const int*)d_in[2];
    const int* j_s = (const int*)d_in[3];
    int n = in_sizes[0] / 3;
    int E = in_sizes[2];
    float* out = (float*)d_out;

    int shift = 8;                                 // 256 particles per coarse bin
    int nbins = ((n - 1) >> shift) + 1;
    while (nbins > 512) { shift++; nbins = ((n - 1) >> shift) + 1; }  // safety
    int jbits = 1;
    while ((1 << jbits) < n) jbits++;              // 17 for n = 100k

    int nbA = (E + CHUNK - 1) / CHUNK;             // 782 hist/split blocks
    int m = nbins * nbA;                           // scan length (~306k)
    int nb2 = (m + 255) / 256;

    char* ws = (char*)d_ws;
    float4* pos4     = (float4*)wcarve(ws, (size_t)n * 16);
    float4* vp4      = (float4*)wcarve(ws, (size_t)n * 16);
    int*    ghist    = (int*)wcarve(ws, (size_t)m * 4);
    int*    gscan    = (int*)wcarve(ws, (size_t)m * 4);
    int*    bsum     = (int*)wcarve(ws, (size_t)nb2 * 4);
    int*    bscan    = (int*)wcarve(ws, (size_t)nb2 * 4);
    int*    pairs    = (int*)wcarve(ws, (size_t)E * 4);
    hf4*    aux      = (hf4*)wcarve(ws, (size_t)E * 8);
    float*  part_rho = (float*)wcarve(ws, (size_t)NSUB * n * 4);
    float4* part_acc4= (float4*)wcarve(ws, (size_t)NSUB * n * 16);

    const int bs = 256;
    int gn = (n + bs - 1) / bs;

    k_pack<<<gn, bs, 0, stream>>>(r, pos4, n);
    k_hist<<<nbA, 256, 0, stream>>>(i_s, ghist, nbA, nbins, E, shift);
    k_scan_block<<<nb2, 256, 0, stream>>>(ghist, gscan, bsum, m);
    k_scan_bsums<<<1, 512, 0, stream>>>(bsum, bscan, nb2);
    k_split<<<nbA, 256, 0, stream>>>(i_s, j_s, ghist, gscan, bscan, pairs, nbA, nbins, E, shift, jbits);
    k_rho_bin<<<nbins * NSUB, 256, 0, stream>>>(pos4, pairs, gscan, bscan, part_rho, aux, nbA, n, E, shift, jbits, nbins);
    k_reduce_rho<<<gn, bs, 0, stream>>>(part_rho, v, vp4, out, n);
    k_acc_bin<<<nbins * NSUB, 256, 0, stream>>>(vp4, pairs, aux, gscan, bscan, part_acc4, nbA, n, E, shift, jbits, nbins);
    k_reduce_acc<<<gn, bs, 0, stream>>>(part_acc4, out, n);
}